// Round 6
// baseline (549.890 us; speedup 1.0000x reference)
//
#include <hip/hip_runtime.h>
#include <math.h>

#define N_NODES 100000
#define N_EDGES 3200000
#define IN_CH 32
#define HID 64
#define BW 512                              // dst nodes per bucket
#define NB ((N_NODES + BW - 1) / BW)        // 196 buckets
#define K3_CHUNK 8192                       // edges per partition block
#define K3_BLOCKS ((N_EDGES + K3_CHUNK - 1) / K3_CHUNK)   // 391
#define NSLICE 4
#define SLICE_CH 16                         // channels per slice (32B bf16)

typedef unsigned short ushort_t;
typedef unsigned long long u64_t;

// ---------------- bf16 helpers ----------------
__device__ __forceinline__ float bflo(unsigned u) { return __uint_as_float(u << 16); }
__device__ __forceinline__ float bfhi(unsigned u) { return __uint_as_float(u & 0xffff0000u); }
__device__ __forceinline__ unsigned packbf(float a, float b) {
    unsigned ua = __float_as_uint(a); ua += 0x7fffu + ((ua >> 16) & 1u);
    unsigned ub = __float_as_uint(b); ub += 0x7fffu + ((ub >> 16) & 1u);
    return (ua >> 16) | (ub & 0xffff0000u);
}

__device__ __forceinline__ int4 nt_load_int4(const int4* p) {
    const int* q = (const int*)p;
    int4 r;
    r.x = __builtin_nontemporal_load(q + 0);
    r.y = __builtin_nontemporal_load(q + 1);
    r.z = __builtin_nontemporal_load(q + 2);
    r.w = __builtin_nontemporal_load(q + 3);
    return r;
}

// ---------------------------------------------------------------------------
// K1: bucket histogram over dst>>9
// ---------------------------------------------------------------------------
__global__ void bucket_hist_kernel(const int* __restrict__ dst, int* __restrict__ bhist) {
    __shared__ int h[NB];
    int t = threadIdx.x;
    for (int i = t; i < NB; i += 256) h[i] = 0;
    __syncthreads();
    const int4* d4 = (const int4*)dst;
    int i0 = blockIdx.x * (K3_CHUNK / 4) + t;
#pragma unroll
    for (int j = 0; j < K3_CHUNK / 1024; ++j) {
        int i4 = i0 + j * 256;
        if (i4 < N_EDGES / 4) {
            int4 d = nt_load_int4(&d4[i4]);
            atomicAdd(&h[d.x >> 9], 1);
            atomicAdd(&h[d.y >> 9], 1);
            atomicAdd(&h[d.z >> 9], 1);
            atomicAdd(&h[d.w >> 9], 1);
        }
    }
    __syncthreads();
    for (int i = t; i < NB; i += 256)
        if (h[i]) atomicAdd(&bhist[i], h[i]);
}

// ---------------------------------------------------------------------------
// K2: exclusive scan of the 196 bucket totals (one block)
// ---------------------------------------------------------------------------
__global__ void scan_buckets_kernel(const int* __restrict__ bhist, int* __restrict__ gbase,
                                    int* __restrict__ gcursor, int* __restrict__ rowptr) {
    __shared__ int sa[256], sb[256];
    int t = threadIdx.x;
    int v = (t < NB) ? bhist[t] : 0;
    sa[t] = v;
    __syncthreads();
    int* pa = sa; int* pb = sb;
    for (int off = 1; off < 256; off <<= 1) {
        int add = (t >= off) ? pa[t - off] : 0;
        pb[t] = pa[t] + add;
        __syncthreads();
        int* tmp = pa; pa = pb; pb = tmp;
    }
    int excl = pa[t] - v;
    if (t <= NB) gbase[t] = (t == NB) ? N_EDGES : excl;
    if (t < NB) gcursor[t] = excl;
    if (t == 0) rowptr[N_NODES] = N_EDGES;
}

// ---------------------------------------------------------------------------
// K3: partition edges into bucket-contiguous packed runs: u = src | ldst<<17
// ---------------------------------------------------------------------------
__global__ void partition_kernel(const int* __restrict__ src, const int* __restrict__ dst,
                                 int* __restrict__ gcursor, int* __restrict__ gsw) {
    __shared__ int h[NB], lbase[NB], lcur[NB];
    int t = threadIdx.x;
    for (int i = t; i < NB; i += 256) { h[i] = 0; lcur[i] = 0; }
    __syncthreads();
    const int4* d4 = (const int4*)dst;
    const int4* s4 = (const int4*)src;
    int i0 = blockIdx.x * (K3_CHUNK / 4) + t;
#pragma unroll
    for (int j = 0; j < K3_CHUNK / 1024; ++j) {
        int i4 = i0 + j * 256;
        if (i4 < N_EDGES / 4) {
            int4 d = d4[i4];
            atomicAdd(&h[d.x >> 9], 1);
            atomicAdd(&h[d.y >> 9], 1);
            atomicAdd(&h[d.z >> 9], 1);
            atomicAdd(&h[d.w >> 9], 1);
        }
    }
    __syncthreads();
    for (int i = t; i < NB; i += 256)
        lbase[i] = h[i] ? atomicAdd(&gcursor[i], h[i]) : 0;
    __syncthreads();
#pragma unroll
    for (int j = 0; j < K3_CHUNK / 1024; ++j) {
        int i4 = i0 + j * 256;
        if (i4 < N_EDGES / 4) {
            int4 d = d4[i4];
            int4 s = s4[i4];
            int b, r;
            b = d.x >> 9; r = atomicAdd(&lcur[b], 1);
            __builtin_nontemporal_store(s.x | ((d.x & (BW - 1)) << 17), &gsw[lbase[b] + r]);
            b = d.y >> 9; r = atomicAdd(&lcur[b], 1);
            __builtin_nontemporal_store(s.y | ((d.y & (BW - 1)) << 17), &gsw[lbase[b] + r]);
            b = d.z >> 9; r = atomicAdd(&lcur[b], 1);
            __builtin_nontemporal_store(s.z | ((d.z & (BW - 1)) << 17), &gsw[lbase[b] + r]);
            b = d.w >> 9; r = atomicAdd(&lcur[b], 1);
            __builtin_nontemporal_store(s.w | ((d.w & (BW - 1)) << 17), &gsw[lbase[b] + r]);
        }
    }
}

// ---------------------------------------------------------------------------
// K4: per-bucket exact CSR placement (rowptr, dinv, esw=src). LDS cursors.
// ---------------------------------------------------------------------------
__global__ __launch_bounds__(512) void bucket_place_kernel(
        const int* __restrict__ gsw, const int* __restrict__ gbase,
        int* __restrict__ rowptr, float* __restrict__ dinv, int* __restrict__ esw) {
    __shared__ int cnt[BW], exc[BW], cur[BW];
    __shared__ int sa[BW], sb[BW];
    int t = threadIdx.x;
    int k = blockIdx.x;
    int d0 = k * BW;
    cnt[t] = 0; cur[t] = 0;
    __syncthreads();
    int beg = gbase[k], end = gbase[k + 1];
    for (int i = beg + t; i < end; i += 512)
        atomicAdd(&cnt[gsw[i] >> 17], 1);
    __syncthreads();
    sa[t] = cnt[t];
    __syncthreads();
    int* pa = sa; int* pb = sb;
    for (int off = 1; off < 512; off <<= 1) {
        int add = (t >= off) ? pa[t - off] : 0;
        pb[t] = pa[t] + add;
        __syncthreads();
        int* tmp = pa; pa = pb; pb = tmp;
    }
    int e_x = pa[t] - cnt[t];
    exc[t] = e_x;
    int d = d0 + t;
    if (d < N_NODES) {
        rowptr[d] = beg + e_x;
        dinv[d] = rsqrtf((float)cnt[t] + 1.0f);
    }
    __syncthreads();
    for (int i = beg + t; i < end; i += 512) {
        int u = gsw[i];
        int ld = u >> 17;
        int r = atomicAdd(&cur[ld], 1);
        esw[beg + exc[ld] + r] = u & 0x1FFFF;
    }
}

// ---------------------------------------------------------------------------
// Hs = (X @ W) * dinv, output bf16 SLICE-MAJOR [4][N][16ch].
// ---------------------------------------------------------------------------
template <int K, bool BF16IN>
__global__ void dense_xw_kernel(const void* __restrict__ Xv, const float* __restrict__ W,
                                const float* __restrict__ dinv, ushort_t* __restrict__ Hs) {
    __shared__ float Wl[K * HID];
    __shared__ float Xl[16 * K];
    int t = threadIdx.x;
    int node0 = blockIdx.x * 16;
    for (int i = t; i < K * HID; i += 256) Wl[i] = W[i];
    if (BF16IN) {
        // X is slice-major bf16 [4][N][16]; 256 threads load one uint2 (4ch) each
        const uint2* X8 = (const uint2*)Xv;
        int slice = t >> 6, nl = (t >> 2) & 15, ci = t & 3;
        uint2 v = X8[((size_t)slice * N_NODES + node0 + nl) * 4 + ci];
        int ch = slice * SLICE_CH + ci * 4;
        Xl[nl * K + ch + 0] = bflo(v.x);
        Xl[nl * K + ch + 1] = bfhi(v.x);
        Xl[nl * K + ch + 2] = bflo(v.y);
        Xl[nl * K + ch + 3] = bfhi(v.y);
    } else {
        const float4* X4 = (const float4*)Xv;
        for (int i = t; i < 16 * K / 4; i += 256)
            ((float4*)Xl)[i] = X4[node0 * K / 4 + i];
    }
    __syncthreads();
    int nl = t >> 4;       // node 0..15
    int c16 = t & 15;      // ch group: ch0 = c16*4
    int node = node0 + nl;
    float s0 = 0.f, s1 = 0.f, s2 = 0.f, s3 = 0.f;
    const float4* Wl4 = (const float4*)Wl;
#pragma unroll
    for (int k = 0; k < K; ++k) {
        float xv = Xl[nl * K + k];
        float4 w = Wl4[k * 16 + c16];
        s0 += xv * w.x; s1 += xv * w.y; s2 += xv * w.z; s3 += xv * w.w;
    }
    float di = dinv[node];
    unsigned lo = packbf(s0 * di, s1 * di);
    unsigned hi = packbf(s2 * di, s3 * di);
    u64_t o = ((u64_t)hi << 32) | lo;
    int slice = c16 >> 2, ci = c16 & 3;
    *(u64_t*)(&((uint2*)Hs)[((size_t)slice * N_NODES + node) * 4 + ci]) = o;
}

// ---------------------------------------------------------------------------
// Sliced gather: pass p aggregates channels [16p, 16p+16) for all nodes.
// Wave per node: 16 edge-groups x 4 lanes x uint2 (8B). Hs slice is L2-hot;
// esw nt-loaded, output nt-stored to protect slice residency.
//   r = relu( dinv[n]*(sum_e Hs[src_e] + Hs[n]) + b )
// ---------------------------------------------------------------------------
__global__ void gather_slice_kernel(const int* __restrict__ esw, const int* __restrict__ rowptr,
                                    const float* __restrict__ dinv, const ushort_t* __restrict__ Hs,
                                    const float* __restrict__ b, ushort_t* __restrict__ Out,
                                    int pass) {
    int t = threadIdx.x;
    int node = blockIdx.x * 4 + (t >> 6);   // N_NODES % 4 == 0
    int lane = t & 63;
    int g = lane >> 2, s = lane & 3;
    int beg = rowptr[node], end = rowptr[node + 1];
    int cnt = end - beg;
    const uint2* H8 = (const uint2*)Hs + (size_t)pass * N_NODES * 4;  // [N][4]
    float4 acc = make_float4(0.f, 0.f, 0.f, 0.f);
    int i = g;
    for (; i + 16 < cnt; i += 32) {
        int s0 = __builtin_nontemporal_load(&esw[beg + i]);
        int s1 = __builtin_nontemporal_load(&esw[beg + i + 16]);
        uint2 v0 = H8[s0 * 4 + s];
        uint2 v1 = H8[s1 * 4 + s];
        acc.x += bflo(v0.x) + bflo(v1.x);
        acc.y += bfhi(v0.x) + bfhi(v1.x);
        acc.z += bflo(v0.y) + bflo(v1.y);
        acc.w += bfhi(v0.y) + bfhi(v1.y);
    }
    if (i < cnt) {
        int s0 = __builtin_nontemporal_load(&esw[beg + i]);
        uint2 v0 = H8[s0 * 4 + s];
        acc.x += bflo(v0.x);
        acc.y += bfhi(v0.x);
        acc.z += bflo(v0.y);
        acc.w += bfhi(v0.y);
    }
    // reduce over the 16 edge-groups (lane bits 2..5)
    acc.x += __shfl_xor(acc.x, 4, 64);  acc.y += __shfl_xor(acc.y, 4, 64);
    acc.z += __shfl_xor(acc.z, 4, 64);  acc.w += __shfl_xor(acc.w, 4, 64);
    acc.x += __shfl_xor(acc.x, 8, 64);  acc.y += __shfl_xor(acc.y, 8, 64);
    acc.z += __shfl_xor(acc.z, 8, 64);  acc.w += __shfl_xor(acc.w, 8, 64);
    acc.x += __shfl_xor(acc.x, 16, 64); acc.y += __shfl_xor(acc.y, 16, 64);
    acc.z += __shfl_xor(acc.z, 16, 64); acc.w += __shfl_xor(acc.w, 16, 64);
    acc.x += __shfl_xor(acc.x, 32, 64); acc.y += __shfl_xor(acc.y, 32, 64);
    acc.z += __shfl_xor(acc.z, 32, 64); acc.w += __shfl_xor(acc.w, 32, 64);

    if (g == 0) {
        uint2 hn = H8[node * 4 + s];
        float di = dinv[node];
        float4 bb = ((const float4*)b)[pass * 4 + s];
        float rx = fmaxf(di * (acc.x + bflo(hn.x)) + bb.x, 0.f);
        float ry = fmaxf(di * (acc.y + bfhi(hn.x)) + bb.y, 0.f);
        float rz = fmaxf(di * (acc.z + bflo(hn.y)) + bb.z, 0.f);
        float rw = fmaxf(di * (acc.w + bfhi(hn.y)) + bb.w, 0.f);
        u64_t o = ((u64_t)packbf(rz, rw) << 32) | packbf(rx, ry);
        __builtin_nontemporal_store(o,
            (u64_t*)&((uint2*)Out)[((size_t)pass * N_NODES + node) * 4 + s]);
    }
}

// ---------------------------------------------------------------------------
// out[n] = sigmoid(dot(B[n,:], Wc) + bc), B slice-major bf16.
// ---------------------------------------------------------------------------
__global__ void classifier_kernel(const ushort_t* __restrict__ B, const float* __restrict__ Wc,
                                  const float* __restrict__ bc, float* __restrict__ out) {
    int t = threadIdx.x;
    int node = blockIdx.x * 16 + (t >> 4);
    int s = t & 15;
    int slice = s >> 2, ci = s & 3;
    uint2 v = ((const uint2*)B)[((size_t)slice * N_NODES + node) * 4 + ci];
    float4 wc = ((const float4*)Wc)[slice * 4 + ci];
    float acc = bflo(v.x) * wc.x + bfhi(v.x) * wc.y + bflo(v.y) * wc.z + bfhi(v.y) * wc.w;
    acc += __shfl_xor(acc, 1, 64);
    acc += __shfl_xor(acc, 2, 64);
    acc += __shfl_xor(acc, 4, 64);
    acc += __shfl_xor(acc, 8, 64);
    if (s == 0) out[node] = 1.0f / (1.0f + expf(-(acc + bc[0])));
}

// ---------------------------------------------------------------------------
extern "C" void kernel_launch(void* const* d_in, const int* in_sizes, int n_in,
                              void* d_out, int out_size, void* d_ws, size_t ws_size,
                              hipStream_t stream) {
    const float* x  = (const float*)d_in[0];
    const int* ei   = (const int*)d_in[1];
    const float* W1 = (const float*)d_in[2];
    const float* b1 = (const float*)d_in[3];
    const float* W2 = (const float*)d_in[4];
    const float* b2 = (const float*)d_in[5];
    const float* Wc = (const float*)d_in[6];
    const float* bc = (const float*)d_in[7];
    float* out = (float*)d_out;

    const int* src = ei;
    const int* dst = ei + N_EDGES;

    // Workspace: gsw[E] int | esw[E] int | rowptr[N+8] | dinv[N] | bhist/gbase/gcursor |
    //            A[N*HID] bf16 slice-major | B[N*HID] bf16 slice-major
    int*   gsw    = (int*)d_ws;
    int*   esw    = gsw + N_EDGES;
    int*   rowptr = esw + N_EDGES;
    float* dinv   = (float*)(rowptr + N_NODES + 8);
    int*   bhist  = (int*)(dinv + N_NODES);
    int*   gbase  = bhist + 256;
    int*   gcursor= gbase + 256;
    ushort_t* A   = (ushort_t*)(gcursor + 256);
    ushort_t* B   = A + (size_t)N_NODES * HID;

    int node16 = N_NODES / 16;   // 6250
    int node4  = N_NODES / 4;    // 25000

    // ---- CSR build ----
    hipMemsetAsync(bhist, 0, 256 * sizeof(int), stream);
    bucket_hist_kernel<<<K3_BLOCKS, 256, 0, stream>>>(dst, bhist);
    scan_buckets_kernel<<<1, 256, 0, stream>>>(bhist, gbase, gcursor, rowptr);
    partition_kernel<<<K3_BLOCKS, 256, 0, stream>>>(src, dst, gcursor, gsw);
    bucket_place_kernel<<<NB, 512, 0, stream>>>(gsw, gbase, rowptr, dinv, esw);

    // ---- layer 1 ----
    dense_xw_kernel<IN_CH, false><<<node16, 256, 0, stream>>>(x, W1, dinv, A);
    for (int p = 0; p < NSLICE; ++p)
        gather_slice_kernel<<<node4, 256, 0, stream>>>(esw, rowptr, dinv, A, b1, B, p);

    // ---- layer 2 ----
    dense_xw_kernel<HID, true><<<node16, 256, 0, stream>>>(B, W2, dinv, A);
    for (int p = 0; p < NSLICE; ++p)
        gather_slice_kernel<<<node4, 256, 0, stream>>>(esw, rowptr, dinv, A, b2, B, p);

    // ---- classifier ----
    classifier_kernel<<<node16, 256, 0, stream>>>(B, Wc, bc, out);
}

// Round 7
// 420.488 us; speedup vs baseline: 1.3077x; 1.3077x over previous
//
#include <hip/hip_runtime.h>
#include <math.h>

#define N_NODES 100000
#define N_EDGES 3200000
#define IN_CH 32
#define HID 64
#define BW 512                              // dst nodes per bucket
#define NB ((N_NODES + BW - 1) / BW)        // 196 buckets
#define K3_CHUNK 8192                       // edges per partition block
#define K3_BLOCKS ((N_EDGES + K3_CHUNK - 1) / K3_CHUNK)   // 391
#define NSLICE 4
#define SLICE_CH 16                         // channels per slice (32B bf16)

typedef unsigned short ushort_t;
typedef unsigned long long u64_t;

// ---------------- bf16 helpers ----------------
__device__ __forceinline__ float bflo(unsigned u) { return __uint_as_float(u << 16); }
__device__ __forceinline__ float bfhi(unsigned u) { return __uint_as_float(u & 0xffff0000u); }
__device__ __forceinline__ unsigned packbf(float a, float b) {
    unsigned ua = __float_as_uint(a); ua += 0x7fffu + ((ua >> 16) & 1u);
    unsigned ub = __float_as_uint(b); ub += 0x7fffu + ((ub >> 16) & 1u);
    return (ua >> 16) | (ub & 0xffff0000u);
}

__device__ __forceinline__ int4 nt_load_int4(const int4* p) {
    const int* q = (const int*)p;
    int4 r;
    r.x = __builtin_nontemporal_load(q + 0);
    r.y = __builtin_nontemporal_load(q + 1);
    r.z = __builtin_nontemporal_load(q + 2);
    r.w = __builtin_nontemporal_load(q + 3);
    return r;
}

// ---------------------------------------------------------------------------
// K1: bucket histogram over dst>>9  (read-once stream: nt-load is fine here)
// ---------------------------------------------------------------------------
__global__ void bucket_hist_kernel(const int* __restrict__ dst, int* __restrict__ bhist) {
    __shared__ int h[NB];
    int t = threadIdx.x;
    for (int i = t; i < NB; i += 256) h[i] = 0;
    __syncthreads();
    const int4* d4 = (const int4*)dst;
    int i0 = blockIdx.x * (K3_CHUNK / 4) + t;
#pragma unroll
    for (int j = 0; j < K3_CHUNK / 1024; ++j) {
        int i4 = i0 + j * 256;
        if (i4 < N_EDGES / 4) {
            int4 d = nt_load_int4(&d4[i4]);
            atomicAdd(&h[d.x >> 9], 1);
            atomicAdd(&h[d.y >> 9], 1);
            atomicAdd(&h[d.z >> 9], 1);
            atomicAdd(&h[d.w >> 9], 1);
        }
    }
    __syncthreads();
    for (int i = t; i < NB; i += 256)
        if (h[i]) atomicAdd(&bhist[i], h[i]);
}

// ---------------------------------------------------------------------------
// K2: exclusive scan of the 196 bucket totals (one block)
// ---------------------------------------------------------------------------
__global__ void scan_buckets_kernel(const int* __restrict__ bhist, int* __restrict__ gbase,
                                    int* __restrict__ gcursor, int* __restrict__ rowptr) {
    __shared__ int sa[256], sb[256];
    int t = threadIdx.x;
    int v = (t < NB) ? bhist[t] : 0;
    sa[t] = v;
    __syncthreads();
    int* pa = sa; int* pb = sb;
    for (int off = 1; off < 256; off <<= 1) {
        int add = (t >= off) ? pa[t - off] : 0;
        pb[t] = pa[t] + add;
        __syncthreads();
        int* tmp = pa; pa = pb; pb = tmp;
    }
    int excl = pa[t] - v;
    if (t <= NB) gbase[t] = (t == NB) ? N_EDGES : excl;
    if (t < NB) gcursor[t] = excl;
    if (t == 0) rowptr[N_NODES] = N_EDGES;
}

// ---------------------------------------------------------------------------
// K3: partition edges into bucket-contiguous packed runs: u = src | ldst<<17
// PLAIN stores — L2 write-combines the scattered 4B stores (nt was 11x ampl.)
// ---------------------------------------------------------------------------
__global__ void partition_kernel(const int* __restrict__ src, const int* __restrict__ dst,
                                 int* __restrict__ gcursor, int* __restrict__ gsw) {
    __shared__ int h[NB], lbase[NB], lcur[NB];
    int t = threadIdx.x;
    for (int i = t; i < NB; i += 256) { h[i] = 0; lcur[i] = 0; }
    __syncthreads();
    const int4* d4 = (const int4*)dst;
    const int4* s4 = (const int4*)src;
    int i0 = blockIdx.x * (K3_CHUNK / 4) + t;
#pragma unroll
    for (int j = 0; j < K3_CHUNK / 1024; ++j) {
        int i4 = i0 + j * 256;
        if (i4 < N_EDGES / 4) {
            int4 d = d4[i4];
            atomicAdd(&h[d.x >> 9], 1);
            atomicAdd(&h[d.y >> 9], 1);
            atomicAdd(&h[d.z >> 9], 1);
            atomicAdd(&h[d.w >> 9], 1);
        }
    }
    __syncthreads();
    for (int i = t; i < NB; i += 256)
        lbase[i] = h[i] ? atomicAdd(&gcursor[i], h[i]) : 0;
    __syncthreads();
#pragma unroll
    for (int j = 0; j < K3_CHUNK / 1024; ++j) {
        int i4 = i0 + j * 256;
        if (i4 < N_EDGES / 4) {
            int4 d = d4[i4];
            int4 s = s4[i4];
            int b, r;
            b = d.x >> 9; r = atomicAdd(&lcur[b], 1);
            gsw[lbase[b] + r] = s.x | ((d.x & (BW - 1)) << 17);
            b = d.y >> 9; r = atomicAdd(&lcur[b], 1);
            gsw[lbase[b] + r] = s.y | ((d.y & (BW - 1)) << 17);
            b = d.z >> 9; r = atomicAdd(&lcur[b], 1);
            gsw[lbase[b] + r] = s.z | ((d.z & (BW - 1)) << 17);
            b = d.w >> 9; r = atomicAdd(&lcur[b], 1);
            gsw[lbase[b] + r] = s.w | ((d.w & (BW - 1)) << 17);
        }
    }
}

// ---------------------------------------------------------------------------
// K4: per-bucket exact CSR placement (rowptr, dinv, esw=src). LDS cursors.
// ---------------------------------------------------------------------------
__global__ __launch_bounds__(512) void bucket_place_kernel(
        const int* __restrict__ gsw, const int* __restrict__ gbase,
        int* __restrict__ rowptr, float* __restrict__ dinv, int* __restrict__ esw) {
    __shared__ int cnt[BW], exc[BW], cur[BW];
    __shared__ int sa[BW], sb[BW];
    int t = threadIdx.x;
    int k = blockIdx.x;
    int d0 = k * BW;
    cnt[t] = 0; cur[t] = 0;
    __syncthreads();
    int beg = gbase[k], end = gbase[k + 1];
    for (int i = beg + t; i < end; i += 512)
        atomicAdd(&cnt[gsw[i] >> 17], 1);
    __syncthreads();
    sa[t] = cnt[t];
    __syncthreads();
    int* pa = sa; int* pb = sb;
    for (int off = 1; off < 512; off <<= 1) {
        int add = (t >= off) ? pa[t - off] : 0;
        pb[t] = pa[t] + add;
        __syncthreads();
        int* tmp = pa; pa = pb; pb = tmp;
    }
    int e_x = pa[t] - cnt[t];
    exc[t] = e_x;
    int d = d0 + t;
    if (d < N_NODES) {
        rowptr[d] = beg + e_x;
        dinv[d] = rsqrtf((float)cnt[t] + 1.0f);
    }
    __syncthreads();
    for (int i = beg + t; i < end; i += 512) {
        int u = gsw[i];
        int ld = u >> 17;
        int r = atomicAdd(&cur[ld], 1);
        esw[beg + exc[ld] + r] = u & 0x1FFFF;
    }
}

// ---------------------------------------------------------------------------
// Hs = (X @ W) * dinv, output bf16 SLICE-MAJOR [4][N][16ch].
// ---------------------------------------------------------------------------
template <int K, bool BF16IN>
__global__ void dense_xw_kernel(const void* __restrict__ Xv, const float* __restrict__ W,
                                const float* __restrict__ dinv, ushort_t* __restrict__ Hs) {
    __shared__ float Wl[K * HID];
    __shared__ float Xl[16 * K];
    int t = threadIdx.x;
    int node0 = blockIdx.x * 16;
    for (int i = t; i < K * HID; i += 256) Wl[i] = W[i];
    if (BF16IN) {
        // X is slice-major bf16 [4][N][16]; 256 threads load one uint2 (4ch) each
        const uint2* X8 = (const uint2*)Xv;
        int slice = t >> 6, nl = (t >> 2) & 15, ci = t & 3;
        uint2 v = X8[((size_t)slice * N_NODES + node0 + nl) * 4 + ci];
        int ch = slice * SLICE_CH + ci * 4;
        Xl[nl * K + ch + 0] = bflo(v.x);
        Xl[nl * K + ch + 1] = bfhi(v.x);
        Xl[nl * K + ch + 2] = bflo(v.y);
        Xl[nl * K + ch + 3] = bfhi(v.y);
    } else {
        const float4* X4 = (const float4*)Xv;
        for (int i = t; i < 16 * K / 4; i += 256)
            ((float4*)Xl)[i] = X4[node0 * K / 4 + i];
    }
    __syncthreads();
    int nl = t >> 4;       // node 0..15
    int c16 = t & 15;      // ch group: ch0 = c16*4
    int node = node0 + nl;
    float s0 = 0.f, s1 = 0.f, s2 = 0.f, s3 = 0.f;
    const float4* Wl4 = (const float4*)Wl;
#pragma unroll
    for (int k = 0; k < K; ++k) {
        float xv = Xl[nl * K + k];
        float4 w = Wl4[k * 16 + c16];
        s0 += xv * w.x; s1 += xv * w.y; s2 += xv * w.z; s3 += xv * w.w;
    }
    float di = dinv[node];
    unsigned lo = packbf(s0 * di, s1 * di);
    unsigned hi = packbf(s2 * di, s3 * di);
    u64_t o = ((u64_t)hi << 32) | lo;
    int slice = c16 >> 2, ci = c16 & 3;
    *(u64_t*)(&((uint2*)Hs)[((size_t)slice * N_NODES + node) * 4 + ci]) = o;
}

// ---------------------------------------------------------------------------
// Sliced gather: pass p aggregates channels [16p, 16p+16) for all nodes.
// Wave per node: 16 edge-groups x 4 lanes x uint2 (8B). Hs slice is L2-hot.
// All plain (cached) accesses — nt hints caused the round-6 regression.
//   r = relu( dinv[n]*(sum_e Hs[src_e] + Hs[n]) + b )
// ---------------------------------------------------------------------------
__global__ void gather_slice_kernel(const int* __restrict__ esw, const int* __restrict__ rowptr,
                                    const float* __restrict__ dinv, const ushort_t* __restrict__ Hs,
                                    const float* __restrict__ b, ushort_t* __restrict__ Out,
                                    int pass) {
    int t = threadIdx.x;
    int node = blockIdx.x * 4 + (t >> 6);   // N_NODES % 4 == 0
    int lane = t & 63;
    int g = lane >> 2, s = lane & 3;
    int beg = rowptr[node], end = rowptr[node + 1];
    int cnt = end - beg;
    const uint2* H8 = (const uint2*)Hs + (size_t)pass * N_NODES * 4;  // [N][4]
    float4 acc = make_float4(0.f, 0.f, 0.f, 0.f);
    int i = g;
    for (; i + 16 < cnt; i += 32) {
        int s0 = esw[beg + i];
        int s1 = esw[beg + i + 16];
        uint2 v0 = H8[s0 * 4 + s];
        uint2 v1 = H8[s1 * 4 + s];
        acc.x += bflo(v0.x) + bflo(v1.x);
        acc.y += bfhi(v0.x) + bfhi(v1.x);
        acc.z += bflo(v0.y) + bflo(v1.y);
        acc.w += bfhi(v0.y) + bfhi(v1.y);
    }
    if (i < cnt) {
        int s0 = esw[beg + i];
        uint2 v0 = H8[s0 * 4 + s];
        acc.x += bflo(v0.x);
        acc.y += bfhi(v0.x);
        acc.z += bflo(v0.y);
        acc.w += bfhi(v0.y);
    }
    // reduce over the 16 edge-groups (lane bits 2..5)
    acc.x += __shfl_xor(acc.x, 4, 64);  acc.y += __shfl_xor(acc.y, 4, 64);
    acc.z += __shfl_xor(acc.z, 4, 64);  acc.w += __shfl_xor(acc.w, 4, 64);
    acc.x += __shfl_xor(acc.x, 8, 64);  acc.y += __shfl_xor(acc.y, 8, 64);
    acc.z += __shfl_xor(acc.z, 8, 64);  acc.w += __shfl_xor(acc.w, 8, 64);
    acc.x += __shfl_xor(acc.x, 16, 64); acc.y += __shfl_xor(acc.y, 16, 64);
    acc.z += __shfl_xor(acc.z, 16, 64); acc.w += __shfl_xor(acc.w, 16, 64);
    acc.x += __shfl_xor(acc.x, 32, 64); acc.y += __shfl_xor(acc.y, 32, 64);
    acc.z += __shfl_xor(acc.z, 32, 64); acc.w += __shfl_xor(acc.w, 32, 64);

    if (g == 0) {
        uint2 hn = H8[node * 4 + s];
        float di = dinv[node];
        float4 bb = ((const float4*)b)[pass * 4 + s];
        float rx = fmaxf(di * (acc.x + bflo(hn.x)) + bb.x, 0.f);
        float ry = fmaxf(di * (acc.y + bfhi(hn.x)) + bb.y, 0.f);
        float rz = fmaxf(di * (acc.z + bflo(hn.y)) + bb.z, 0.f);
        float rw = fmaxf(di * (acc.w + bfhi(hn.y)) + bb.w, 0.f);
        u64_t o = ((u64_t)packbf(rz, rw) << 32) | packbf(rx, ry);
        *(u64_t*)&((uint2*)Out)[((size_t)pass * N_NODES + node) * 4 + s] = o;
    }
}

// ---------------------------------------------------------------------------
// out[n] = sigmoid(dot(B[n,:], Wc) + bc), B slice-major bf16.
// ---------------------------------------------------------------------------
__global__ void classifier_kernel(const ushort_t* __restrict__ B, const float* __restrict__ Wc,
                                  const float* __restrict__ bc, float* __restrict__ out) {
    int t = threadIdx.x;
    int node = blockIdx.x * 16 + (t >> 4);
    int s = t & 15;
    int slice = s >> 2, ci = s & 3;
    uint2 v = ((const uint2*)B)[((size_t)slice * N_NODES + node) * 4 + ci];
    float4 wc = ((const float4*)Wc)[slice * 4 + ci];
    float acc = bflo(v.x) * wc.x + bfhi(v.x) * wc.y + bflo(v.y) * wc.z + bfhi(v.y) * wc.w;
    acc += __shfl_xor(acc, 1, 64);
    acc += __shfl_xor(acc, 2, 64);
    acc += __shfl_xor(acc, 4, 64);
    acc += __shfl_xor(acc, 8, 64);
    if (s == 0) out[node] = 1.0f / (1.0f + expf(-(acc + bc[0])));
}

// ---------------------------------------------------------------------------
extern "C" void kernel_launch(void* const* d_in, const int* in_sizes, int n_in,
                              void* d_out, int out_size, void* d_ws, size_t ws_size,
                              hipStream_t stream) {
    const float* x  = (const float*)d_in[0];
    const int* ei   = (const int*)d_in[1];
    const float* W1 = (const float*)d_in[2];
    const float* b1 = (const float*)d_in[3];
    const float* W2 = (const float*)d_in[4];
    const float* b2 = (const float*)d_in[5];
    const float* Wc = (const float*)d_in[6];
    const float* bc = (const float*)d_in[7];
    float* out = (float*)d_out;

    const int* src = ei;
    const int* dst = ei + N_EDGES;

    // Workspace: gsw[E] int | esw[E] int | rowptr[N+8] | dinv[N] | bhist/gbase/gcursor |
    //            A[N*HID] bf16 slice-major | B[N*HID] bf16 slice-major
    int*   gsw    = (int*)d_ws;
    int*   esw    = gsw + N_EDGES;
    int*   rowptr = esw + N_EDGES;
    float* dinv   = (float*)(rowptr + N_NODES + 8);
    int*   bhist  = (int*)(dinv + N_NODES);
    int*   gbase  = bhist + 256;
    int*   gcursor= gbase + 256;
    ushort_t* A   = (ushort_t*)(gcursor + 256);
    ushort_t* B   = A + (size_t)N_NODES * HID;

    int node16 = N_NODES / 16;   // 6250
    int node4  = N_NODES / 4;    // 25000

    // ---- CSR build ----
    hipMemsetAsync(bhist, 0, 256 * sizeof(int), stream);
    bucket_hist_kernel<<<K3_BLOCKS, 256, 0, stream>>>(dst, bhist);
    scan_buckets_kernel<<<1, 256, 0, stream>>>(bhist, gbase, gcursor, rowptr);
    partition_kernel<<<K3_BLOCKS, 256, 0, stream>>>(src, dst, gcursor, gsw);
    bucket_place_kernel<<<NB, 512, 0, stream>>>(gsw, gbase, rowptr, dinv, esw);

    // ---- layer 1 ----
    dense_xw_kernel<IN_CH, false><<<node16, 256, 0, stream>>>(x, W1, dinv, A);
    for (int p = 0; p < NSLICE; ++p)
        gather_slice_kernel<<<node4, 256, 0, stream>>>(esw, rowptr, dinv, A, b1, B, p);

    // ---- layer 2 ----
    dense_xw_kernel<HID, true><<<node16, 256, 0, stream>>>(B, W2, dinv, A);
    for (int p = 0; p < NSLICE; ++p)
        gather_slice_kernel<<<node4, 256, 0, stream>>>(esw, rowptr, dinv, A, b2, B, p);

    // ---- classifier ----
    classifier_kernel<<<node16, 256, 0, stream>>>(B, Wc, bc, out);
}

// Round 8
// 322.261 us; speedup vs baseline: 1.7063x; 1.3048x over previous
//
#include <hip/hip_runtime.h>
#include <math.h>

#define N_NODES 100000
#define N_EDGES 3200000
#define IN_CH 32
#define HID 64
#define BW 256                               // dst nodes per bucket
#define NB ((N_NODES + BW - 1) / BW)         // 391 buckets
#define CAP 9216                             // fixed slot capacity per bucket
#define NCPY 4                               // histogram/cursor replication
#define K3_CHUNK 8192                        // edges per partition block
#define K3_BLOCKS ((N_EDGES + K3_CHUNK - 1) / K3_CHUNK)   // 391

typedef unsigned short ushort_t;
typedef unsigned long long u64_t;

// ---------------- bf16 helpers ----------------
__device__ __forceinline__ float bflo(unsigned u) { return __uint_as_float(u << 16); }
__device__ __forceinline__ float bfhi(unsigned u) { return __uint_as_float(u & 0xffff0000u); }
__device__ __forceinline__ unsigned packbf(float a, float b) {
    unsigned ua = __float_as_uint(a); ua += 0x7fffu + ((ua >> 16) & 1u);
    unsigned ub = __float_as_uint(b); ub += 0x7fffu + ((ub >> 16) & 1u);
    return (ua >> 16) | (ub & 0xffff0000u);
}

// ---------------------------------------------------------------------------
// K1: partition edges into FIXED-capacity bucket regions; counts -> gcursor.
// 512 thr/block, 4-way replicated LDS hist+cursors (contention fix).
// Payload: u = src | local_dst<<17  (src < 2^17, local_dst < 256)
// ---------------------------------------------------------------------------
__global__ __launch_bounds__(512) void partition_kernel(
        const int* __restrict__ src, const int* __restrict__ dst,
        int* __restrict__ gcursor, int* __restrict__ gsw) {
    __shared__ int h[NCPY][NB], lbase[NCPY][NB], lcur[NCPY][NB];
    int t = threadIdx.x;
    int c = t & (NCPY - 1);
    for (int i = t; i < NCPY * NB; i += 512) {
        ((int*)h)[i] = 0;
        ((int*)lcur)[i] = 0;
    }
    __syncthreads();
    const int4* d4 = (const int4*)dst;
    const int4* s4 = (const int4*)src;
    int i0 = blockIdx.x * (K3_CHUNK / 4) + t;
#pragma unroll
    for (int j = 0; j < K3_CHUNK / 2048; ++j) {      // 4 int4 per thread
        int i4 = i0 + j * 512;
        if (i4 < N_EDGES / 4) {
            int4 d = d4[i4];
            atomicAdd(&h[c][d.x >> 8], 1);
            atomicAdd(&h[c][d.y >> 8], 1);
            atomicAdd(&h[c][d.z >> 8], 1);
            atomicAdd(&h[c][d.w >> 8], 1);
        }
    }
    __syncthreads();
    // reserve per-(copy,bucket) ranges in the fixed region
    for (int i = t; i < NCPY * NB; i += 512) {
        int cc = i / NB, bb = i - cc * NB;
        int n = h[cc][bb];
        lbase[cc][bb] = n ? atomicAdd(&gcursor[bb], n) : 0;
    }
    __syncthreads();
#pragma unroll
    for (int j = 0; j < K3_CHUNK / 2048; ++j) {
        int i4 = i0 + j * 512;
        if (i4 < N_EDGES / 4) {
            int4 d = d4[i4];
            int4 s = s4[i4];
            int b, r, idx;
            b = d.x >> 8; r = atomicAdd(&lcur[c][b], 1); idx = lbase[c][b] + r;
            if (idx < CAP) gsw[(size_t)b * CAP + idx] = s.x | ((d.x & (BW - 1)) << 17);
            b = d.y >> 8; r = atomicAdd(&lcur[c][b], 1); idx = lbase[c][b] + r;
            if (idx < CAP) gsw[(size_t)b * CAP + idx] = s.y | ((d.y & (BW - 1)) << 17);
            b = d.z >> 8; r = atomicAdd(&lcur[c][b], 1); idx = lbase[c][b] + r;
            if (idx < CAP) gsw[(size_t)b * CAP + idx] = s.z | ((d.z & (BW - 1)) << 17);
            b = d.w >> 8; r = atomicAdd(&lcur[c][b], 1); idx = lbase[c][b] + r;
            if (idx < CAP) gsw[(size_t)b * CAP + idx] = s.w | ((d.w & (BW - 1)) << 17);
        }
    }
}

// ---------------------------------------------------------------------------
// K2: exclusive scan of 391 bucket counts -> gbase (compact esw bases)
// ---------------------------------------------------------------------------
__global__ __launch_bounds__(512) void scan_buckets_kernel(
        const int* __restrict__ gcursor, int* __restrict__ gbase,
        int* __restrict__ rowptr) {
    __shared__ int sa[512], sb[512];
    int t = threadIdx.x;
    int v = (t < NB) ? gcursor[t] : 0;
    sa[t] = v;
    __syncthreads();
    int* pa = sa; int* pb = sb;
    for (int off = 1; off < 512; off <<= 1) {
        int add = (t >= off) ? pa[t - off] : 0;
        pb[t] = pa[t] + add;
        __syncthreads();
        int* tmp = pa; pa = pb; pb = tmp;
    }
    int excl = pa[t] - v;
    if (t <= NB) gbase[t] = (t == NB) ? N_EDGES : excl;
    if (t == 0) rowptr[N_NODES] = N_EDGES;
}

// ---------------------------------------------------------------------------
// K3: per-bucket exact CSR placement (rowptr, dinv, compact esw=src).
// ---------------------------------------------------------------------------
__global__ __launch_bounds__(512) void bucket_place_kernel(
        const int* __restrict__ gsw, const int* __restrict__ gcursor,
        const int* __restrict__ gbase,
        int* __restrict__ rowptr, float* __restrict__ dinv, int* __restrict__ esw) {
    __shared__ int cnt[BW], exc[BW], cur[BW];
    __shared__ int sa[BW], sb[BW];
    int t = threadIdx.x;
    int k = blockIdx.x;
    int d0 = k * BW;
    if (t < BW) { cnt[t] = 0; cur[t] = 0; }
    __syncthreads();
    int total = gcursor[k];
    const int* reg = gsw + (size_t)k * CAP;
    for (int i = t; i < total; i += 512)
        atomicAdd(&cnt[reg[i] >> 17], 1);
    __syncthreads();
    if (t < BW) sa[t] = cnt[t];
    __syncthreads();
    int* pa = sa; int* pb = sb;
    for (int off = 1; off < BW; off <<= 1) {
        if (t < BW) {
            int add = (t >= off) ? pa[t - off] : 0;
            pb[t] = pa[t] + add;
        }
        __syncthreads();
        int* tmp = pa; pa = pb; pb = tmp;
    }
    int cbase = gbase[k];
    if (t < BW) {
        int e_x = pa[t] - cnt[t];
        exc[t] = e_x;
        int d = d0 + t;
        if (d < N_NODES) {
            rowptr[d] = cbase + e_x;
            dinv[d] = rsqrtf((float)cnt[t] + 1.0f);
        }
    }
    __syncthreads();
    for (int i = t; i < total; i += 512) {
        int u = reg[i];
        int ld = u >> 17;
        int r = atomicAdd(&cur[ld], 1);
        esw[cbase + exc[ld] + r] = u & 0x1FFFF;
    }
}

// ---------------------------------------------------------------------------
// Hs = (X @ W) * dinv, output bf16 row-major [N][64]. 16 nodes/block.
// Thread (nl = t>>4, c16 = t&15) computes 4 channels, writes one 8B store.
// ---------------------------------------------------------------------------
template <int K, bool BF16IN>
__global__ void dense_xw_kernel(const void* __restrict__ Xv, const float* __restrict__ W,
                                const float* __restrict__ dinv, ushort_t* __restrict__ Hs) {
    __shared__ float Wl[K * HID];
    __shared__ float Xl[16 * K];
    int t = threadIdx.x;
    int node0 = blockIdx.x * 16;
    for (int i = t; i < K * HID; i += 256) Wl[i] = W[i];
    if (BF16IN) {
        // X row-major bf16 [N][64]: 256 threads load one uint2 (4 ch) each
        const uint2* X8 = (const uint2*)Xv;
        int nl = t >> 4, ci = t & 15;
        uint2 v = X8[(size_t)(node0 + nl) * 16 + ci];
        Xl[nl * K + ci * 4 + 0] = bflo(v.x);
        Xl[nl * K + ci * 4 + 1] = bfhi(v.x);
        Xl[nl * K + ci * 4 + 2] = bflo(v.y);
        Xl[nl * K + ci * 4 + 3] = bfhi(v.y);
    } else {
        const float4* X4 = (const float4*)Xv;
        for (int i = t; i < 16 * K / 4; i += 256)
            ((float4*)Xl)[i] = X4[node0 * K / 4 + i];
    }
    __syncthreads();
    int nl = t >> 4;       // node 0..15
    int c16 = t & 15;      // channel group: ch0 = c16*4
    int node = node0 + nl;
    float s0 = 0.f, s1 = 0.f, s2 = 0.f, s3 = 0.f;
    const float4* Wl4 = (const float4*)Wl;
#pragma unroll
    for (int k = 0; k < K; ++k) {
        float xv = Xl[nl * K + k];
        float4 w = Wl4[k * 16 + c16];
        s0 += xv * w.x; s1 += xv * w.y; s2 += xv * w.z; s3 += xv * w.w;
    }
    float di = dinv[node];
    u64_t o = ((u64_t)packbf(s2 * di, s3 * di) << 32) | packbf(s0 * di, s1 * di);
    *(u64_t*)(Hs + (size_t)node * HID + c16 * 4) = o;
}

// ---------------------------------------------------------------------------
// Gather-aggregate over bf16 Hs rows (round-4 proven form).
// Wave per node: 4 edge-groups x 16 lanes x uint2 (8B) -> 128B row reads.
//   r = relu( dinv[n]*(sum_e Hs[src_e] + Hs[n]) + b )
// FUSE_CLS: fold sigmoid classifier (layer 2), else write bf16 r.
// ---------------------------------------------------------------------------
template <bool FUSE_CLS>
__global__ void gather_agg_kernel(const int* __restrict__ esw, const int* __restrict__ rowptr,
                                  const float* __restrict__ dinv, const ushort_t* __restrict__ Hs,
                                  const float* __restrict__ b,
                                  const float* __restrict__ Wc, const float* __restrict__ bc,
                                  void* __restrict__ Outv) {
    int t = threadIdx.x;
    int node = blockIdx.x * 4 + (t >> 6);   // N_NODES % 4 == 0
    int lane = t & 63;
    int g = lane >> 4, s = lane & 15;
    int beg = rowptr[node], end = rowptr[node + 1];
    int cnt = end - beg;
    const uint2* H8 = (const uint2*)Hs;     // 8B = 4 bf16 channels
    float4 acc = make_float4(0.f, 0.f, 0.f, 0.f);
    int i = g;
    for (; i + 12 < cnt; i += 16) {
        int s0 = esw[beg + i];
        int s1 = esw[beg + i + 4];
        int s2 = esw[beg + i + 8];
        int s3 = esw[beg + i + 12];
        uint2 v0 = H8[s0 * 16 + s];
        uint2 v1 = H8[s1 * 16 + s];
        uint2 v2 = H8[s2 * 16 + s];
        uint2 v3 = H8[s3 * 16 + s];
        acc.x += (bflo(v0.x) + bflo(v1.x)) + (bflo(v2.x) + bflo(v3.x));
        acc.y += (bfhi(v0.x) + bfhi(v1.x)) + (bfhi(v2.x) + bfhi(v3.x));
        acc.z += (bflo(v0.y) + bflo(v1.y)) + (bflo(v2.y) + bflo(v3.y));
        acc.w += (bfhi(v0.y) + bfhi(v1.y)) + (bfhi(v2.y) + bfhi(v3.y));
    }
    for (; i < cnt; i += 4) {
        int s0 = esw[beg + i];
        uint2 v0 = H8[s0 * 16 + s];
        acc.x += bflo(v0.x);
        acc.y += bfhi(v0.x);
        acc.z += bflo(v0.y);
        acc.w += bfhi(v0.y);
    }
    // reduce across the 4 edge-groups
    acc.x += __shfl_xor(acc.x, 16, 64); acc.y += __shfl_xor(acc.y, 16, 64);
    acc.z += __shfl_xor(acc.z, 16, 64); acc.w += __shfl_xor(acc.w, 16, 64);
    acc.x += __shfl_xor(acc.x, 32, 64); acc.y += __shfl_xor(acc.y, 32, 64);
    acc.z += __shfl_xor(acc.z, 32, 64); acc.w += __shfl_xor(acc.w, 32, 64);

    uint2 hn = H8[node * 16 + s];
    float di = dinv[node];
    float4 bb = ((const float4*)b)[s];
    float rx = fmaxf(di * (acc.x + bflo(hn.x)) + bb.x, 0.f);
    float ry = fmaxf(di * (acc.y + bfhi(hn.x)) + bb.y, 0.f);
    float rz = fmaxf(di * (acc.z + bflo(hn.y)) + bb.z, 0.f);
    float rw = fmaxf(di * (acc.w + bfhi(hn.y)) + bb.w, 0.f);

    if (!FUSE_CLS) {
        if (g == 0) {
            u64_t o = ((u64_t)packbf(rz, rw) << 32) | packbf(rx, ry);
            *(u64_t*)((ushort_t*)Outv + (size_t)node * HID + s * 4) = o;
        }
    } else {
        float4 wc = ((const float4*)Wc)[s];
        float v = rx * wc.x + ry * wc.y + rz * wc.z + rw * wc.w;
#pragma unroll
        for (int off = 1; off < 16; off <<= 1) v += __shfl_xor(v, off, 64);
        if (lane == 0) ((float*)Outv)[node] = 1.0f / (1.0f + expf(-(v + bc[0])));
    }
}

// ---------------------------------------------------------------------------
extern "C" void kernel_launch(void* const* d_in, const int* in_sizes, int n_in,
                              void* d_out, int out_size, void* d_ws, size_t ws_size,
                              hipStream_t stream) {
    const float* x  = (const float*)d_in[0];
    const int* ei   = (const int*)d_in[1];
    const float* W1 = (const float*)d_in[2];
    const float* b1 = (const float*)d_in[3];
    const float* W2 = (const float*)d_in[4];
    const float* b2 = (const float*)d_in[5];
    const float* Wc = (const float*)d_in[6];
    const float* bc = (const float*)d_in[7];
    float* out = (float*)d_out;

    const int* src = ei;
    const int* dst = ei + N_EDGES;

    // Workspace: gsw[NB*CAP] int | esw[E] int | rowptr[N+8] | dinv[N] |
    //            gcursor[512] | gbase[512] | A[N*64] bf16 | B[N*64] bf16
    int*   gsw    = (int*)d_ws;
    int*   esw    = gsw + (size_t)NB * CAP;
    int*   rowptr = esw + N_EDGES;
    float* dinv   = (float*)(rowptr + N_NODES + 8);
    int*   gcursor= (int*)(dinv + N_NODES);
    int*   gbase  = gcursor + 512;
    ushort_t* A   = (ushort_t*)(gbase + 512);
    ushort_t* B   = A + (size_t)N_NODES * HID;

    int node16 = N_NODES / 16;   // 6250
    int node4  = N_NODES / 4;    // 25000

    // ---- CSR build (fixed-capacity bucket sort) ----
    hipMemsetAsync(gcursor, 0, NB * sizeof(int), stream);
    partition_kernel<<<K3_BLOCKS, 512, 0, stream>>>(src, dst, gcursor, gsw);
    scan_buckets_kernel<<<1, 512, 0, stream>>>(gcursor, gbase, rowptr);
    bucket_place_kernel<<<NB, 512, 0, stream>>>(gsw, gcursor, gbase, rowptr, dinv, esw);

    // ---- layer 1 ----
    dense_xw_kernel<IN_CH, false><<<node16, 256, 0, stream>>>(x, W1, dinv, A);
    gather_agg_kernel<false><<<node4, 256, 0, stream>>>(esw, rowptr, dinv, A, b1,
                                                        nullptr, nullptr, B);

    // ---- layer 2 + fused classifier ----
    dense_xw_kernel<HID, true><<<node16, 256, 0, stream>>>(B, W2, dinv, A);
    gather_agg_kernel<true><<<node4, 256, 0, stream>>>(esw, rowptr, dinv, A, b2,
                                                       Wc, bc, out);
}